// Round 1
// baseline (11870.024 us; speedup 1.0000x reference)
//
#include <hip/hip_runtime.h>
#include <math.h>

#define NB   512   // batch
#define TENC 128   // encoder steps
#define FDEC 32    // decoder steps
#define HD   512   // hidden
#define TTOT 160   // TENC + FDEC

// ---------------------------------------------------------------------------
// Layer-1 LSTM step: gates = h1@Whh1^T + x_t*Wih1 + b; cell update.
// Tile: 64 samples (blockIdx.y) x 16 hidden dims (blockIdx.x), all 4 gates
// fused per thread. 256 threads: tm=tid&15 -> 4 samples, td=tid>>4 -> 1 dim.
// K staged in 32-wide chunks, LDS stored transposed [k][row] for b128 reads,
// register-prefetch double buffering to hide global latency at 1 wave/SIMD.
// ---------------------------------------------------------------------------
__global__ __launch_bounds__(256) void lstm1_step(
    const float* __restrict__ hin, float* __restrict__ hout,
    float* __restrict__ c1,
    const float* __restrict__ Whh, const float* __restrict__ Wih,
    const float* __restrict__ bih, const float* __restrict__ bhh,
    const float* __restrict__ x, const float* __restrict__ tgt,
    const int* __restrict__ tfm, const float* __restrict__ outp,
    int t)
{
  __shared__ float Hs[2][32][68];   // [buf][k][sample(64)+pad]
  __shared__ float Ws[2][32][68];   // [buf][k][dr*4+gate(64)+pad]

  const int tid = threadIdx.x;
  const int d0  = blockIdx.x * 16;
  const int n0  = blockIdx.y * 64;
  const int tm  = tid & 15;
  const int td  = tid >> 4;
  const int lr  = tid >> 3;          // 0..31 (staging row)
  const int lc  = (tid & 7) << 2;    // 0,4,...,28 (staging k base)

  float acc[4][4];
#pragma unroll
  for (int s = 0; s < 4; ++s)
#pragma unroll
    for (int g = 0; g < 4; ++g) acc[s][g] = 0.f;

  float4 hA[2], wA[2];

  // prologue: chunk 0 -> regs -> LDS buf 0
#pragma unroll
  for (int p = 0; p < 2; ++p) {
    int r = lr + p * 32;
    hA[p] = *(const float4*)&hin[(n0 + r) * HD + lc];
    int dr = r >> 2, g = r & 3;
    wA[p] = *(const float4*)&Whh[(g * HD + d0 + dr) * HD + lc];
  }
#pragma unroll
  for (int p = 0; p < 2; ++p) {
    int r = lr + p * 32;
    Hs[0][lc+0][r] = hA[p].x; Hs[0][lc+1][r] = hA[p].y;
    Hs[0][lc+2][r] = hA[p].z; Hs[0][lc+3][r] = hA[p].w;
    Ws[0][lc+0][r] = wA[p].x; Ws[0][lc+1][r] = wA[p].y;
    Ws[0][lc+2][r] = wA[p].z; Ws[0][lc+3][r] = wA[p].w;
  }
  __syncthreads();

  for (int ci = 0; ci < 16; ++ci) {
    const int buf = ci & 1;
    if (ci + 1 < 16) {
      const int kc = (ci + 1) * 32;
#pragma unroll
      for (int p = 0; p < 2; ++p) {
        int r = lr + p * 32;
        hA[p] = *(const float4*)&hin[(n0 + r) * HD + kc + lc];
        int dr = r >> 2, g = r & 3;
        wA[p] = *(const float4*)&Whh[(g * HD + d0 + dr) * HD + kc + lc];
      }
    }
#pragma unroll
    for (int k = 0; k < 32; ++k) {
      float4 hv = *(const float4*)&Hs[buf][k][tm << 2];
      float4 wv = *(const float4*)&Ws[buf][k][td << 2];
      acc[0][0] = fmaf(hv.x, wv.x, acc[0][0]);
      acc[0][1] = fmaf(hv.x, wv.y, acc[0][1]);
      acc[0][2] = fmaf(hv.x, wv.z, acc[0][2]);
      acc[0][3] = fmaf(hv.x, wv.w, acc[0][3]);
      acc[1][0] = fmaf(hv.y, wv.x, acc[1][0]);
      acc[1][1] = fmaf(hv.y, wv.y, acc[1][1]);
      acc[1][2] = fmaf(hv.y, wv.z, acc[1][2]);
      acc[1][3] = fmaf(hv.y, wv.w, acc[1][3]);
      acc[2][0] = fmaf(hv.z, wv.x, acc[2][0]);
      acc[2][1] = fmaf(hv.z, wv.y, acc[2][1]);
      acc[2][2] = fmaf(hv.z, wv.z, acc[2][2]);
      acc[2][3] = fmaf(hv.z, wv.w, acc[2][3]);
      acc[3][0] = fmaf(hv.w, wv.x, acc[3][0]);
      acc[3][1] = fmaf(hv.w, wv.y, acc[3][1]);
      acc[3][2] = fmaf(hv.w, wv.z, acc[3][2]);
      acc[3][3] = fmaf(hv.w, wv.w, acc[3][3]);
    }
    if (ci + 1 < 16) {
      const int nb = buf ^ 1;
#pragma unroll
      for (int p = 0; p < 2; ++p) {
        int r = lr + p * 32;
        Hs[nb][lc+0][r] = hA[p].x; Hs[nb][lc+1][r] = hA[p].y;
        Hs[nb][lc+2][r] = hA[p].z; Hs[nb][lc+3][r] = hA[p].w;
        Ws[nb][lc+0][r] = wA[p].x; Ws[nb][lc+1][r] = wA[p].y;
        Ws[nb][lc+2][r] = wA[p].z; Ws[nb][lc+3][r] = wA[p].w;
      }
    }
    __syncthreads();
  }

  // epilogue: add x*Wih + biases, LSTM cell
  const int d = d0 + td;
  float wi[4], bs[4];
#pragma unroll
  for (int g = 0; g < 4; ++g) {
    int row = g * HD + d;
    wi[g] = Wih[row];            // W_ih1 is [4H,1]
    bs[g] = bih[row] + bhh[row];
  }
#pragma unroll
  for (int s = 0; s < 4; ++s) {
    int n = n0 + (tm << 2) + s;
    float xv;
    if (t < TENC) {
      xv = x[n * TENC + t];
    } else {
      int j = t - TENC;
      xv = (tfm[j] > 0) ? tgt[n * FDEC + j] : outp[n * TTOT + t - 1];
    }
    float pi = acc[s][0] + xv * wi[0] + bs[0];
    float pf = acc[s][1] + xv * wi[1] + bs[1];
    float pg = acc[s][2] + xv * wi[2] + bs[2];
    float po = acc[s][3] + xv * wi[3] + bs[3];
    float ig = 1.f / (1.f + expf(-pi));
    float fg = 1.f / (1.f + expf(-pf));
    float gv = tanhf(pg);
    float og = 1.f / (1.f + expf(-po));
    int idx = n * HD + d;
    float c = fg * c1[idx] + ig * gv;
    c1[idx] = c;
    hout[idx] = og * tanhf(c);
  }
}

// ---------------------------------------------------------------------------
// Layer-2 LSTM step: gates = h1'@Wih2^T + h2@Whh2^T + b (K=1024 as two
// staged phases); cell update; fused FC (out = h2'.wfc + bfc) via block
// reduction + atomicAdd into d_out.
// ---------------------------------------------------------------------------
__global__ __launch_bounds__(256) void lstm2_step(
    const float* __restrict__ h1c, const float* __restrict__ h2i,
    float* __restrict__ h2o, float* __restrict__ c2,
    const float* __restrict__ Wih2, const float* __restrict__ Whh2,
    const float* __restrict__ bih, const float* __restrict__ bhh,
    const float* __restrict__ wfc, const float* __restrict__ bfc,
    float* __restrict__ outp, int t)
{
  __shared__ float Hs[2][32][68];
  __shared__ float Ws[2][32][68];
  __shared__ float red[64][17];

  const int tid = threadIdx.x;
  const int d0  = blockIdx.x * 16;
  const int n0  = blockIdx.y * 64;
  const int tm  = tid & 15;
  const int td  = tid >> 4;
  const int lr  = tid >> 3;
  const int lc  = (tid & 7) << 2;

  float acc[4][4];
#pragma unroll
  for (int s = 0; s < 4; ++s)
#pragma unroll
    for (int g = 0; g < 4; ++g) acc[s][g] = 0.f;

  float4 hA[2], wA[2];

  // prologue: chunk 0 (phase 1: h1', Wih2)
#pragma unroll
  for (int p = 0; p < 2; ++p) {
    int r = lr + p * 32;
    hA[p] = *(const float4*)&h1c[(n0 + r) * HD + lc];
    int dr = r >> 2, g = r & 3;
    wA[p] = *(const float4*)&Wih2[(g * HD + d0 + dr) * HD + lc];
  }
#pragma unroll
  for (int p = 0; p < 2; ++p) {
    int r = lr + p * 32;
    Hs[0][lc+0][r] = hA[p].x; Hs[0][lc+1][r] = hA[p].y;
    Hs[0][lc+2][r] = hA[p].z; Hs[0][lc+3][r] = hA[p].w;
    Ws[0][lc+0][r] = wA[p].x; Ws[0][lc+1][r] = wA[p].y;
    Ws[0][lc+2][r] = wA[p].z; Ws[0][lc+3][r] = wA[p].w;
  }
  __syncthreads();

  for (int ci = 0; ci < 32; ++ci) {
    const int buf = ci & 1;
    if (ci + 1 < 32) {
      const float* Hsrc = (ci + 1 < 16) ? h1c : h2i;
      const float* Wsrc = (ci + 1 < 16) ? Wih2 : Whh2;
      const int kc = ((ci + 1) & 15) * 32;
#pragma unroll
      for (int p = 0; p < 2; ++p) {
        int r = lr + p * 32;
        hA[p] = *(const float4*)&Hsrc[(n0 + r) * HD + kc + lc];
        int dr = r >> 2, g = r & 3;
        wA[p] = *(const float4*)&Wsrc[(g * HD + d0 + dr) * HD + kc + lc];
      }
    }
#pragma unroll
    for (int k = 0; k < 32; ++k) {
      float4 hv = *(const float4*)&Hs[buf][k][tm << 2];
      float4 wv = *(const float4*)&Ws[buf][k][td << 2];
      acc[0][0] = fmaf(hv.x, wv.x, acc[0][0]);
      acc[0][1] = fmaf(hv.x, wv.y, acc[0][1]);
      acc[0][2] = fmaf(hv.x, wv.z, acc[0][2]);
      acc[0][3] = fmaf(hv.x, wv.w, acc[0][3]);
      acc[1][0] = fmaf(hv.y, wv.x, acc[1][0]);
      acc[1][1] = fmaf(hv.y, wv.y, acc[1][1]);
      acc[1][2] = fmaf(hv.y, wv.z, acc[1][2]);
      acc[1][3] = fmaf(hv.y, wv.w, acc[1][3]);
      acc[2][0] = fmaf(hv.z, wv.x, acc[2][0]);
      acc[2][1] = fmaf(hv.z, wv.y, acc[2][1]);
      acc[2][2] = fmaf(hv.z, wv.z, acc[2][2]);
      acc[2][3] = fmaf(hv.z, wv.w, acc[2][3]);
      acc[3][0] = fmaf(hv.w, wv.x, acc[3][0]);
      acc[3][1] = fmaf(hv.w, wv.y, acc[3][1]);
      acc[3][2] = fmaf(hv.w, wv.z, acc[3][2]);
      acc[3][3] = fmaf(hv.w, wv.w, acc[3][3]);
    }
    if (ci + 1 < 32) {
      const int nb = buf ^ 1;
#pragma unroll
      for (int p = 0; p < 2; ++p) {
        int r = lr + p * 32;
        Hs[nb][lc+0][r] = hA[p].x; Hs[nb][lc+1][r] = hA[p].y;
        Hs[nb][lc+2][r] = hA[p].z; Hs[nb][lc+3][r] = hA[p].w;
        Ws[nb][lc+0][r] = wA[p].x; Ws[nb][lc+1][r] = wA[p].y;
        Ws[nb][lc+2][r] = wA[p].z; Ws[nb][lc+3][r] = wA[p].w;
      }
    }
    __syncthreads();
  }

  const int d = d0 + td;
  float bs[4];
#pragma unroll
  for (int g = 0; g < 4; ++g) {
    int row = g * HD + d;
    bs[g] = bih[row] + bhh[row];
  }
  const float wf = wfc[d];
  float psum[4];
#pragma unroll
  for (int s = 0; s < 4; ++s) {
    int n = n0 + (tm << 2) + s;
    float pi = acc[s][0] + bs[0];
    float pf = acc[s][1] + bs[1];
    float pg = acc[s][2] + bs[2];
    float po = acc[s][3] + bs[3];
    float ig = 1.f / (1.f + expf(-pi));
    float fg = 1.f / (1.f + expf(-pf));
    float gv = tanhf(pg);
    float og = 1.f / (1.f + expf(-po));
    int idx = n * HD + d;
    float c = fg * c2[idx] + ig * gv;
    c2[idx] = c;
    float h = og * tanhf(c);
    h2o[idx] = h;
    psum[s] = h * wf;
  }
#pragma unroll
  for (int s = 0; s < 4; ++s) red[(tm << 2) + s][td] = psum[s];
  __syncthreads();
  if (tid < 64) {
    float sum = 0.f;
#pragma unroll
    for (int q = 0; q < 16; ++q) sum += red[tid][q];
    if (blockIdx.x == 0) sum += bfc[0];
    atomicAdd(&outp[(n0 + tid) * TTOT + t], sum);
  }
}

// ---------------------------------------------------------------------------
extern "C" void kernel_launch(void* const* d_in, const int* in_sizes, int n_in,
                              void* d_out, int out_size, void* d_ws, size_t ws_size,
                              hipStream_t stream)
{
  const float* x    = (const float*)d_in[0];
  const float* tgt  = (const float*)d_in[1];
  const int*   tfm  = (const int*)  d_in[2];
  // d_in[3] = future (constant 32, baked in)
  const float* Wih1 = (const float*)d_in[4];
  const float* Whh1 = (const float*)d_in[5];
  const float* bih1 = (const float*)d_in[6];
  const float* bhh1 = (const float*)d_in[7];
  const float* Wih2 = (const float*)d_in[8];
  const float* Whh2 = (const float*)d_in[9];
  const float* bih2 = (const float*)d_in[10];
  const float* bhh2 = (const float*)d_in[11];
  const float* wfc  = (const float*)d_in[12];
  const float* bfc  = (const float*)d_in[13];

  float* outp = (float*)d_out;
  float* ws   = (float*)d_ws;
  const int NHbuf = NB * HD;      // 262144 floats
  float* h1 = ws;                 // [2][N*H] double buffered
  float* c1 = ws + 2 * NHbuf;
  float* h2 = ws + 3 * NHbuf;     // [2][N*H]
  float* c2 = ws + 5 * NHbuf;

  hipMemsetAsync(d_ws, 0, (size_t)6 * NHbuf * sizeof(float), stream);
  hipMemsetAsync(d_out, 0, (size_t)NB * TTOT * sizeof(float), stream);

  dim3 grid(32, 8), blk(256);
  for (int t = 0; t < TTOT; ++t) {
    int p = t & 1;
    lstm1_step<<<grid, blk, 0, stream>>>(
        h1 + p * NHbuf, h1 + (p ^ 1) * NHbuf, c1,
        Whh1, Wih1, bih1, bhh1, x, tgt, tfm, outp, t);
    lstm2_step<<<grid, blk, 0, stream>>>(
        h1 + (p ^ 1) * NHbuf, h2 + p * NHbuf, h2 + (p ^ 1) * NHbuf, c2,
        Wih2, Whh2, bih2, bhh2, wfc, bfc, outp, t);
  }
}

// Round 6
// 5686.993 us; speedup vs baseline: 2.0872x; 2.0872x over previous
//
#include <hip/hip_runtime.h>
#include <math.h>

#define NB   512
#define TENC 128
#define FDEC 32
#define TTOT 160
#define HD   512

typedef unsigned short ushort_t;
typedef short  short8  __attribute__((ext_vector_type(8)));
typedef float  f32x16  __attribute__((ext_vector_type(16)));

__device__ __forceinline__ unsigned short f2bf(float f) {
  unsigned u = __float_as_uint(f);
  u += 0x7FFFu + ((u >> 16) & 1u);          // RNE
  return (unsigned short)(u >> 16);
}
__device__ __forceinline__ float bf2f(unsigned short h) {
  return __uint_as_float(((unsigned)h) << 16);
}

__device__ __forceinline__ void gll16(const void* g, void* l) {
  __builtin_amdgcn_global_load_lds(
      (const __attribute__((address_space(1))) void*)g,
      (__attribute__((address_space(3))) void*)l, 16, 0, 0);
}

// stage 4 tiles (A_hi, A_lo, B_hi, B_lo) of one K=32 chunk into LDS buffer.
// LDS slot layout per tile: [(ksub*2+kgroup)=w][row=lane] x 16B. Wave w stages
// k-group w (k offset w*8), lane = row. Sources pre-offset to kc.
__device__ __forceinline__ void stage_tiles(short* lds, int buf, int w,
    const unsigned short* ah, const unsigned short* al,
    const unsigned short* bh, const unsigned short* bl) {
  short* db = lds + buf * 8192 + w * 512;
  gll16(ah, db);
  gll16(al, db + 2048);
  gll16(bh, db + 4096);
  gll16(bl, db + 6144);
}

// one K=32 chunk: 2 ksub x 3 compensated MFMAs
__device__ __forceinline__ void compute_chunk(const short* B, int aoff, int boff,
                                              f32x16& acc) {
#pragma unroll
  for (int ks = 0; ks < 2; ++ks) {
    short8 ah = *(const short8*)(B + aoff +        ks * 1024);
    short8 al = *(const short8*)(B + aoff + 2048 + ks * 1024);
    short8 bh = *(const short8*)(B + boff +        ks * 1024);
    short8 bl = *(const short8*)(B + boff + 2048 + ks * 1024);
    acc = __builtin_amdgcn_mfma_f32_32x32x16_bf16(ah, bh, acc, 0, 0, 0);
    acc = __builtin_amdgcn_mfma_f32_32x32x16_bf16(ah, bl, acc, 0, 0, 0);
    acc = __builtin_amdgcn_mfma_f32_32x32x16_bf16(al, bh, acc, 0, 0, 0);
  }
}

// ---------------------------------------------------------------------------
// split weights into hi/lo bf16, rows permuted to j = d*4 + gate.
// W1 (from Whh1): [2048][512].  W2cat (Wih2|Whh2): [2048][1024].
// ---------------------------------------------------------------------------
__global__ __launch_bounds__(256) void split_w(
    const float* __restrict__ Whh1, const float* __restrict__ Wih2,
    const float* __restrict__ Whh2,
    unsigned short* __restrict__ W1h, unsigned short* __restrict__ W1l,
    unsigned short* __restrict__ W2h, unsigned short* __restrict__ W2l)
{
  int idx = blockIdx.x * 256 + threadIdx.x;
  if (idx < 2048 * 64) {               // W1: groups of 8 k
    int j = idx >> 6, kg = (idx & 63) << 3;
    const float* s = Whh1 + (size_t)((j & 3) * HD + (j >> 2)) * HD + kg;
    unsigned short* oh = W1h + (size_t)j * HD + kg;
    unsigned short* ol = W1l + (size_t)j * HD + kg;
#pragma unroll
    for (int i = 0; i < 8; ++i) {
      float v = s[i];
      unsigned short h = f2bf(v);
      oh[i] = h; ol[i] = f2bf(v - bf2f(h));
    }
  } else {
    int q = idx - 2048 * 64;
    if (q >= 2048 * 128) return;
    int j = q >> 7, kg = (q & 127) << 3;
    int srow = (j & 3) * HD + (j >> 2);
    const float* s = (kg < 512) ? (Wih2 + (size_t)srow * HD + kg)
                                : (Whh2 + (size_t)srow * HD + (kg - 512));
    unsigned short* oh = W2h + (size_t)j * 1024 + kg;
    unsigned short* ol = W2l + (size_t)j * 1024 + kg;
#pragma unroll
    for (int i = 0; i < 8; ++i) {
      float v = s[i];
      unsigned short h = f2bf(v);
      oh[i] = h; ol[i] = f2bf(v - bf2f(h));
    }
  }
}

// ---------------------------------------------------------------------------
// Layer-1 step: gates[n][j=d*4+g] = h(t-1) @ W1^T (split-bf16 MFMA), + x*Wih1
// + biases, cell, write h as hi/lo bf16. Block: 64 batch x 64 j. 4 waves of
// 32x32. K=512 in 16 chunks, 3-buffer LDS, 2-deep gll prefetch.
// ---------------------------------------------------------------------------
__global__ __launch_bounds__(256) void lstm1_step(
    const unsigned short* __restrict__ hinH, const unsigned short* __restrict__ hinL,
    unsigned short* __restrict__ houtH, unsigned short* __restrict__ houtL,
    float* __restrict__ c1,
    const unsigned short* __restrict__ WH, const unsigned short* __restrict__ WL,
    const float* __restrict__ Wih, const float* __restrict__ bih,
    const float* __restrict__ bhh,
    const float* __restrict__ x, const float* __restrict__ tgt,
    const int* __restrict__ tfm, const float* __restrict__ outp, int t)
{
  __shared__ short lds[3 * 8192];      // 48 KB: 3 bufs x 4 tiles x 4KB
  const int tid = threadIdx.x;
  const int w = tid >> 6, l = tid & 63;
  const int j0 = blockIdx.x * 64;
  const int n0 = blockIdx.y * 64;
  const int moff = (w >> 1) * 32, noff = (w & 1) * 32;
  const int lan = l & 31, kg = l >> 5;

  const unsigned short* gAh = hinH + (size_t)(n0 + l) * HD + w * 8;
  const unsigned short* gAl = hinL + (size_t)(n0 + l) * HD + w * 8;
  const unsigned short* gBh = WH   + (size_t)(j0 + l) * HD + w * 8;
  const unsigned short* gBl = WL   + (size_t)(j0 + l) * HD + w * 8;

  const int aoff = (kg * 64 + moff + lan) * 8;
  const int boff = 4096 + (kg * 64 + noff + lan) * 8;

  f32x16 acc;
#pragma unroll
  for (int r = 0; r < 16; ++r) acc[r] = 0.f;

  stage_tiles(lds, 0, w, gAh,      gAl,      gBh,      gBl);
  stage_tiles(lds, 1, w, gAh + 32, gAl + 32, gBh + 32, gBl + 32);
  asm volatile("s_waitcnt vmcnt(4)" ::: "memory");
  __builtin_amdgcn_s_barrier();
  __builtin_amdgcn_sched_barrier(0);

  for (int c = 0; c < 16; ++c) {
    if (c + 2 < 16) {
      int kc = (c + 2) * 32;
      stage_tiles(lds, (c + 2) % 3, w, gAh + kc, gAl + kc, gBh + kc, gBl + kc);
    }
    compute_chunk(lds + (c % 3) * 8192, aoff, boff, acc);
    if (c + 1 < 16) {
      if (c + 2 < 16) asm volatile("s_waitcnt vmcnt(4)" ::: "memory");
      else            asm volatile("s_waitcnt vmcnt(0)" ::: "memory");
      __builtin_amdgcn_s_barrier();
      __builtin_amdgcn_sched_barrier(0);
    }
  }
  __syncthreads();

  // gate exchange through LDS: Gs[j_local(64)][row(64)+pad2]
  float* Gs = (float*)lds;
#pragma unroll
  for (int r = 0; r < 16; ++r) {
    int row = (r & 3) + 8 * (r >> 2) + 4 * kg;
    Gs[(noff + lan) * 66 + moff + row] = acc[r];
  }
  __syncthreads();

  const int dl = tid & 15, q = tid >> 4;
  const int dg = blockIdx.x * 16 + dl;
  float wi[4], bsum[4];
#pragma unroll
  for (int g4 = 0; g4 < 4; ++g4) {
    int row = g4 * HD + dg;
    wi[g4] = Wih[row];
    bsum[g4] = bih[row] + bhh[row];
  }
#pragma unroll
  for (int jj = 0; jj < 4; ++jj) {
    int nloc = q * 4 + jj, n = n0 + nloc;
    float xv;
    if (t < TENC) xv = x[n * TENC + t];
    else {
      int j2 = t - TENC;
      xv = (tfm[j2] > 0) ? tgt[n * FDEC + j2] : outp[n * TTOT + t - 1];
    }
    float p0 = Gs[(dl * 4 + 0) * 66 + nloc] + xv * wi[0] + bsum[0];
    float p1 = Gs[(dl * 4 + 1) * 66 + nloc] + xv * wi[1] + bsum[1];
    float p2 = Gs[(dl * 4 + 2) * 66 + nloc] + xv * wi[2] + bsum[2];
    float p3 = Gs[(dl * 4 + 3) * 66 + nloc] + xv * wi[3] + bsum[3];
    float ig = 1.f / (1.f + expf(-p0));
    float fg = 1.f / (1.f + expf(-p1));
    float gv = tanhf(p2);
    float og = 1.f / (1.f + expf(-p3));
    int idx = n * HD + dg;
    float c = fg * c1[idx] + ig * gv;
    c1[idx] = c;
    float h = og * tanhf(c);
    unsigned short hh = f2bf(h);
    houtH[idx] = hh;
    houtL[idx] = f2bf(h - bf2f(hh));
  }
}

// ---------------------------------------------------------------------------
// Layer-2 step: K=1024 (h1 current | h2 prev), cell, h2 hi/lo write, FC
// partial reduce + atomicAdd into out.
// ---------------------------------------------------------------------------
__global__ __launch_bounds__(256) void lstm2_step(
    const unsigned short* __restrict__ a1H, const unsigned short* __restrict__ a1L,
    const unsigned short* __restrict__ a2H, const unsigned short* __restrict__ a2L,
    unsigned short* __restrict__ houtH, unsigned short* __restrict__ houtL,
    float* __restrict__ c2,
    const unsigned short* __restrict__ WH, const unsigned short* __restrict__ WL,
    const float* __restrict__ bih, const float* __restrict__ bhh,
    const float* __restrict__ wfc, const float* __restrict__ bfc,
    float* __restrict__ outp, int t)
{
  __shared__ short lds[3 * 8192];
  const int tid = threadIdx.x;
  const int w = tid >> 6, l = tid & 63;
  const int j0 = blockIdx.x * 64;
  const int n0 = blockIdx.y * 64;
  const int moff = (w >> 1) * 32, noff = (w & 1) * 32;
  const int lan = l & 31, kg = l >> 5;

  const unsigned short* g1H = a1H + (size_t)(n0 + l) * HD + w * 8;
  const unsigned short* g1L = a1L + (size_t)(n0 + l) * HD + w * 8;
  const unsigned short* g2H = a2H + (size_t)(n0 + l) * HD + w * 8;
  const unsigned short* g2L = a2L + (size_t)(n0 + l) * HD + w * 8;
  const unsigned short* gBh = WH + (size_t)(j0 + l) * 1024 + w * 8;
  const unsigned short* gBl = WL + (size_t)(j0 + l) * 1024 + w * 8;

  const int aoff = (kg * 64 + moff + lan) * 8;
  const int boff = 4096 + (kg * 64 + noff + lan) * 8;

  f32x16 acc;
#pragma unroll
  for (int r = 0; r < 16; ++r) acc[r] = 0.f;

#define STAGE2(cc, bb) { int kc = (cc) * 32;                                   \
    const unsigned short *sah, *sal;                                           \
    if (kc < 512) { sah = g1H + kc;       sal = g1L + kc; }                    \
    else          { sah = g2H + kc - 512; sal = g2L + kc - 512; }              \
    stage_tiles(lds, bb, w, sah, sal, gBh + kc, gBl + kc); }

  STAGE2(0, 0);
  STAGE2(1, 1);
  asm volatile("s_waitcnt vmcnt(4)" ::: "memory");
  __builtin_amdgcn_s_barrier();
  __builtin_amdgcn_sched_barrier(0);

  for (int c = 0; c < 32; ++c) {
    if (c + 2 < 32) STAGE2(c + 2, (c + 2) % 3);
    compute_chunk(lds + (c % 3) * 8192, aoff, boff, acc);
    if (c + 1 < 32) {
      if (c + 2 < 32) asm volatile("s_waitcnt vmcnt(4)" ::: "memory");
      else            asm volatile("s_waitcnt vmcnt(0)" ::: "memory");
      __builtin_amdgcn_s_barrier();
      __builtin_amdgcn_sched_barrier(0);
    }
  }
#undef STAGE2
  __syncthreads();

  float* Gs = (float*)lds;                       // [64][66]
  float* Rd = (float*)lds + 64 * 66;             // [64][17]
#pragma unroll
  for (int r = 0; r < 16; ++r) {
    int row = (r & 3) + 8 * (r >> 2) + 4 * kg;
    Gs[(noff + lan) * 66 + moff + row] = acc[r];
  }
  __syncthreads();

  const int dl = tid & 15, q = tid >> 4;
  const int dg = blockIdx.x * 16 + dl;
  float bsum[4];
#pragma unroll
  for (int g4 = 0; g4 < 4; ++g4) bsum[g4] = bih[g4 * HD + dg] + bhh[g4 * HD + dg];
  const float wf = wfc[dg];
#pragma unroll
  for (int jj = 0; jj < 4; ++jj) {
    int nloc = q * 4 + jj, n = n0 + nloc;
    float p0 = Gs[(dl * 4 + 0) * 66 + nloc] + bsum[0];
    float p1 = Gs[(dl * 4 + 1) * 66 + nloc] + bsum[1];
    float p2 = Gs[(dl * 4 + 2) * 66 + nloc] + bsum[2];
    float p3 = Gs[(dl * 4 + 3) * 66 + nloc] + bsum[3];
    float ig = 1.f / (1.f + expf(-p0));
    float fg = 1.f / (1.f + expf(-p1));
    float gv = tanhf(p2);
    float og = 1.f / (1.f + expf(-p3));
    int idx = n * HD + dg;
    float c = fg * c2[idx] + ig * gv;
    c2[idx] = c;
    float h = og * tanhf(c);
    unsigned short hh = f2bf(h);
    houtH[idx] = hh;
    houtL[idx] = f2bf(h - bf2f(hh));
    Rd[nloc * 17 + dl] = h * wf;
  }
  __syncthreads();
  if (tid < 64) {
    float sum = 0.f;
#pragma unroll
    for (int k = 0; k < 16; ++k) sum += Rd[tid * 17 + k];
    if (blockIdx.x == 0) sum += bfc[0];
    atomicAdd(&outp[(n0 + tid) * TTOT + t], sum);
  }
}

// ---------------------------------------------------------------------------
extern "C" void kernel_launch(void* const* d_in, const int* in_sizes, int n_in,
                              void* d_out, int out_size, void* d_ws, size_t ws_size,
                              hipStream_t stream)
{
  const float* x    = (const float*)d_in[0];
  const float* tgt  = (const float*)d_in[1];
  const int*   tfm  = (const int*)  d_in[2];
  const float* Wih1 = (const float*)d_in[4];
  const float* Whh1 = (const float*)d_in[5];
  const float* bih1 = (const float*)d_in[6];
  const float* bhh1 = (const float*)d_in[7];
  const float* Wih2 = (const float*)d_in[8];
  const float* Whh2 = (const float*)d_in[9];
  const float* bih2 = (const float*)d_in[10];
  const float* bhh2 = (const float*)d_in[11];
  const float* wfc  = (const float*)d_in[12];
  const float* bfc  = (const float*)d_in[13];
  float* outp = (float*)d_out;

  const size_t W1E = 2048 * 512, W2E = 2048 * 1024, HE = 512 * 512;
  unsigned short* W1h = (unsigned short*)d_ws;
  unsigned short* W1l = W1h + W1E;
  unsigned short* W2h = W1l + W1E;
  unsigned short* W2l = W2h + W2E;
  unsigned short* h1H = W2l + W2E;          // [2][HE]
  unsigned short* h1L = h1H + 2 * HE;
  unsigned short* h2H = h1L + 2 * HE;
  unsigned short* h2L = h2H + 2 * HE;
  float* c1 = (float*)(h2L + 2 * HE);
  float* c2 = c1 + HE;

  hipMemsetAsync(h1H, 0, 8 * HE * sizeof(unsigned short) + 2 * HE * sizeof(float), stream);
  hipMemsetAsync(d_out, 0, (size_t)NB * TTOT * sizeof(float), stream);

  split_w<<<1536, 256, 0, stream>>>(Whh1, Wih2, Whh2, W1h, W1l, W2h, W2l);

  dim3 grid(32, 8), blk(256);
  for (int t = 0; t < TTOT; ++t) {
    int p = t & 1;
    lstm1_step<<<grid, blk, 0, stream>>>(
        h1H + p * HE, h1L + p * HE, h1H + (p ^ 1) * HE, h1L + (p ^ 1) * HE,
        c1, W1h, W1l, Wih1, bih1, bhh1, x, tgt, tfm, outp, t);
    lstm2_step<<<grid, blk, 0, stream>>>(
        h1H + (p ^ 1) * HE, h1L + (p ^ 1) * HE, h2H + p * HE, h2L + p * HE,
        h2H + (p ^ 1) * HE, h2L + (p ^ 1) * HE,
        c2, W2h, W2l, bih2, bhh2, wfc, bfc, outp, t);
  }
}